// Round 1
// baseline (832.746 us; speedup 1.0000x reference)
//
#include <hip/hip_runtime.h>
#include <math.h>

// Problem constants
#define NB 4
#define NC 128
#define NH 128
#define NW 128
#define NHW (NH*NW)
#define NCOUT 128
#define NOFF 54

// ws float offsets
#define SY_OFF 0
#define SX_OFF 1179648
#define MK_OFF 2359296
#define WT_OFF 3538944
#define WS_FLOATS 3686400   // ~14.75 MB

// ---------------------------------------------------------------------------
// Kernel A: 3x3 offset conv (54 out channels), writes processed sy/sx/mask.
// Block = (b, ho). 256 threads: wo = tid&127, half = tid>>7 (wave-uniform).
// Thread accumulates 27 channels: c = 2*j + half.
// ---------------------------------------------------------------------------
__global__ __launch_bounds__(256) void offconv_kernel(
    const float* __restrict__ x, const float* __restrict__ w_off,
    const float* __restrict__ b_off, float* __restrict__ ws)
{
    __shared__ float xr[32][3][130];   // 32 cin x 3 rows x (128 + 2 halo)
    const int tid = threadIdx.x;
    const int b  = blockIdx.x >> 7;
    const int ho = blockIdx.x & 127;
    const int wo = tid & 127;
    const int half = tid >> 7;                       // wave-uniform
    const int half_u = __builtin_amdgcn_readfirstlane(half);

    float acc[27];
#pragma unroll
    for (int j = 0; j < 27; ++j) acc[j] = 0.f;

    for (int c0 = 0; c0 < NC; c0 += 32) {
        // stage 32 cin x 3 rows (with zero-padded halo)
        for (int idx = tid; idx < 32*390; idx += 256) {
            int ci = idx / 390;
            int r  = idx - ci*390;
            int ky = r / 130;
            int cc = r - ky*130;          // 0..129 -> col = cc-1
            int y  = ho - 1 + ky;
            int col = cc - 1;
            float v = 0.f;
            if ((unsigned)y < NH && (unsigned)col < NW)
                v = x[((b*NC + c0 + ci)*NH + y)*NW + col];
            xr[ci][ky][cc] = v;
        }
        __syncthreads();
#pragma unroll 1
        for (int ci = 0; ci < 32; ++ci) {
            float xv[9];
#pragma unroll
            for (int ky = 0; ky < 3; ++ky)
#pragma unroll
                for (int kx = 0; kx < 3; ++kx)
                    xv[ky*3+kx] = xr[ci][ky][wo + kx];
            const int cin = c0 + ci;
#pragma unroll
            for (int j = 0; j < 27; ++j) {
                const float* wp = w_off + ((2*j + half_u)*NC + cin)*9; // uniform -> s_load
                acc[j] += wp[0]*xv[0] + wp[1]*xv[1] + wp[2]*xv[2]
                        + wp[3]*xv[3] + wp[4]*xv[4] + wp[5]*xv[5]
                        + wp[6]*xv[6] + wp[7]*xv[7] + wp[8]*xv[8];
            }
        }
        __syncthreads();
    }

    // Epilogue: channel c<36 -> offsets (d=0 -> sy, d=1 -> sx); c>=36 -> sigmoid mask
#pragma unroll
    for (int j = 0; j < 27; ++j) {
        const int c = 2*j + half;
        float v = acc[j] + b_off[c];
        int og, k2;
        int dst_off;
        if (c < 36) {
            og = c / 18;
            int rem = c - og*18;
            k2 = rem >> 1;
            dst_off = (c & 1) ? SX_OFF : SY_OFF;
        } else {
            v = 1.f / (1.f + expf(-v));
            int cc = c - 36;
            og = cc / 9;
            k2 = cc - og*9;
            dst_off = MK_OFF;
        }
        ws[dst_off + (((b*2 + og)*9 + k2)*NHW) + ho*NW + wo] = v;
    }
}

// ---------------------------------------------------------------------------
// Kernel C: transpose weight [O][CIN][3][3] -> wT[k2][cin][o] (contiguous in o)
// ---------------------------------------------------------------------------
__global__ void wtrans_kernel(const float* __restrict__ w, float* __restrict__ ws)
{
    int i = blockIdx.x*256 + threadIdx.x;
    if (i >= NCOUT*NC*9) return;
    int k2 = i % 9;
    int t  = i / 9;
    int cin = t % NC;
    int o   = t / NC;
    ws[WT_OFF + (k2*NC + cin)*NCOUT + o] = w[i];
}

// ---------------------------------------------------------------------------
// Kernel B: fused bilinear sampling + main GEMM.
// Block = 64 pixels (half a row) x all 128 couts. 256 threads.
//   sampling: p = tid&63 (consecutive pixels -> coalesced gathers),
//             cin block = (tid>>6)*32 (og fixed per thread).
//   GEMM: cgrp = tid>>6 owns couts cgrp*32..+31, lanes = pixels.
// ---------------------------------------------------------------------------
__global__ __launch_bounds__(256) void deform_kernel(
    const float* __restrict__ x, const float* __restrict__ ws,
    const float* __restrict__ bias, float* __restrict__ out)
{
    __shared__ float vals[128][64];     // 32 KB, conflict-free (2-way is free)
    __shared__ int4  sI[2][64];
    __shared__ float4 sW[2][64];

    const int tid  = threadIdx.x;
    const int tile = blockIdx.x;           // 0..1023
    const int b    = tile >> 8;
    const int pb   = (tile & 255) * 64;    // pixel base within image
    const int ho   = pb >> 7;
    const int wo0  = pb & 127;
    const int p    = tid & 63;
    const int cq   = tid >> 6;             // 0..3, wave-uniform
    const int cin0 = cq * 32;
    const int og_s = cq >> 1;
    const int cgrp = __builtin_amdgcn_readfirstlane(cq);

    const float* syA = ws + SY_OFF;
    const float* sxA = ws + SX_OFF;
    const float* mkA = ws + MK_OFF;
    const float* wT  = ws + WT_OFF;

    float acc[32];
#pragma unroll
    for (int j = 0; j < 32; ++j) acc[j] = 0.f;

    for (int k2 = 0; k2 < 9; ++k2) {
        // ---- prep: bilinear indices + validity-folded weights (threads 0..127)
        if (tid < 128) {
            const int og = tid >> 6;
            const int pp = tid & 63;
            const int wo = wo0 + pp;
            const int sidx = (((b*2 + og)*9 + k2)*NHW) + pb + pp;
            const float sy = (float)(ho - 1 + k2/3) + syA[sidx];
            const float sx = (float)(wo - 1 + k2%3) + sxA[sidx];
            const float m  = mkA[sidx];
            const float y0f = floorf(sy);
            const float x0f = floorf(sx);
            const float ly = sy - y0f;
            const float lx = sx - x0f;
            const int y0 = (int)y0f, x0 = (int)x0f;
            const int y1 = y0 + 1,  x1 = x0 + 1;
            const bool vy0 = (unsigned)y0 < NH;
            const bool vy1 = (unsigned)y1 < NH;
            const bool vx0 = (unsigned)x0 < NW;
            const bool vx1 = (unsigned)x1 < NW;
            const int cy0 = min(max(y0, 0), NH-1);
            const int cy1 = min(max(y1, 0), NH-1);
            const int cx0 = min(max(x0, 0), NW-1);
            const int cx1 = min(max(x1, 0), NW-1);
            int4 I;
            I.x = cy0*NW + cx0;
            I.y = cy0*NW + cx1;
            I.z = cy1*NW + cx0;
            I.w = cy1*NW + cx1;
            float4 Wv;
            Wv.x = (vy0 && vx0) ? (1.f-ly)*(1.f-lx)*m : 0.f;
            Wv.y = (vy0 && vx1) ? (1.f-ly)*lx*m       : 0.f;
            Wv.z = (vy1 && vx0) ? ly*(1.f-lx)*m       : 0.f;
            Wv.w = (vy1 && vx1) ? ly*lx*m             : 0.f;
            sI[og][pp] = I;
            sW[og][pp] = Wv;
        }
        __syncthreads();

        // ---- sampling: each thread fills vals[cin0..cin0+31][p]
        {
            const int4  I  = sI[og_s][p];
            const float4 Wv = sW[og_s][p];
            const float* xb = x + (long)(b*NC + cin0)*NHW;
#pragma unroll 4
            for (int i = 0; i < 32; ++i) {
                const float* xp = xb + i*NHW;
                vals[cin0 + i][p] = Wv.x*xp[I.x] + Wv.y*xp[I.y]
                                  + Wv.z*xp[I.z] + Wv.w*xp[I.w];
            }
        }
        __syncthreads();

        // ---- GEMM accumulate: acc[j] += wT[k2][cin][cgrp*32+j] * vals[cin][p]
        {
            const float* wk = wT + (k2*NC)*NCOUT + cgrp*32;
#pragma unroll 2
            for (int cin = 0; cin < NC; ++cin) {
                const float v = vals[cin][p];
                const float* wr = wk + cin*NCOUT;   // wave-uniform -> s_load_dwordx16
#pragma unroll
                for (int j = 0; j < 32; ++j)
                    acc[j] += wr[j] * v;
            }
        }
        __syncthreads();
    }

    // ---- epilogue: bias + store (lanes = consecutive pixels, coalesced)
    float* ob = out + (long)(b*NCOUT)*NHW + pb + p;
#pragma unroll
    for (int j = 0; j < 32; ++j) {
        const int o = cgrp*32 + j;
        ob[(long)o*NHW] = acc[j] + bias[o];
    }
}

// ---------------------------------------------------------------------------
extern "C" void kernel_launch(void* const* d_in, const int* in_sizes, int n_in,
                              void* d_out, int out_size, void* d_ws, size_t ws_size,
                              hipStream_t stream)
{
    const float* x      = (const float*)d_in[0];
    const float* w_off  = (const float*)d_in[1];
    const float* b_off  = (const float*)d_in[2];
    const float* weight = (const float*)d_in[3];
    const float* bias   = (const float*)d_in[4];
    float* out = (float*)d_out;
    float* ws  = (float*)d_ws;

    hipLaunchKernelGGL(offconv_kernel, dim3(NB*NH), dim3(256), 0, stream,
                       x, w_off, b_off, ws);
    hipLaunchKernelGGL(wtrans_kernel, dim3((NCOUT*NC*9 + 255)/256), dim3(256), 0, stream,
                       weight, ws);
    hipLaunchKernelGGL(deform_kernel, dim3(NB*NHW/64), dim3(256), 0, stream,
                       x, ws, bias, out);
}

// Round 2
// 366.692 us; speedup vs baseline: 2.2710x; 2.2710x over previous
//
#include <hip/hip_runtime.h>
#include <math.h>

#define NB 4
#define NC 128
#define NH 128
#define NW 128
#define NHW (NH*NW)
#define NCOUT 128

// ws float offsets
#define SY_OFF 0
#define SX_OFF 1179648
#define MK_OFF 2359296
#define WOFF_OFF 3538944    // bf16 wA_off: 64*1152 shorts (=36864 floats)
#define WMAIN_OFF 3575808   // bf16 wA_main: 128*1152 shorts (=73728 floats)

typedef short short8 __attribute__((ext_vector_type(8)));
typedef float f32x4 __attribute__((ext_vector_type(4)));

__device__ inline short f2bf(float f) {
    unsigned u = __float_as_uint(f);
    u = (u + 0x7FFFu + ((u >> 16) & 1u)) >> 16;   // RNE
    return (short)u;
}
__device__ inline unsigned pack2(float lo, float hi) {
    return ((unsigned)(unsigned short)f2bf(lo)) |
           (((unsigned)(unsigned short)f2bf(hi)) << 16);
}

// ---------------------------------------------------------------------------
// wtrans: build bf16 weight tables [cout][k2][cin] (offset conv padded to 64)
// ---------------------------------------------------------------------------
__global__ void wtrans_kernel(const float* __restrict__ w_off,
                              const float* __restrict__ weight,
                              float* __restrict__ ws)
{
    int i = blockIdx.x * 256 + threadIdx.x;
    if (i < 64*1152) {
        int cout = i / 1152, rem = i - cout*1152;
        int k2 = rem >> 7, cin = rem & 127;
        float v = (cout < 54) ? w_off[(cout*NC + cin)*9 + k2] : 0.f;
        ((short*)(ws + WOFF_OFF))[i] = f2bf(v);
    } else if (i < 64*1152 + 128*1152) {
        int j = i - 64*1152;
        int cout = j / 1152, rem = j - cout*1152;
        int k2 = rem >> 7, cin = rem & 127;
        ((short*)(ws + WMAIN_OFF))[j] = f2bf(weight[(cout*NC + cin)*9 + k2]);
    }
}

// ---------------------------------------------------------------------------
// offconv: 3x3 conv, 54 ch (pad 64) via MFMA. Block = (b, ho, half-row 64px).
// 256 threads = 4 waves; wave w owns all 64 couts x 16 px (px0 = 16w).
// ---------------------------------------------------------------------------
__global__ __launch_bounds__(256) void offconv_kernel(
    const float* __restrict__ x, const float* __restrict__ b_off,
    float* __restrict__ ws)
{
    __shared__ short xs[3][66][40];   // [ky][col(-1..64)][32 cin + pad8], 80B rows
    int bid = blockIdx.x;
    bid = (bid & 7) * 128 + (bid >> 3);     // XCD swizzle (1024 = 8*128, bijective)
    const int b   = bid >> 8;
    const int ho  = (bid >> 1) & 127;
    const int wb  = (bid & 1) * 64;
    const int tid = threadIdx.x;
    const int lane = tid & 63;
    const int wid = tid >> 6;
    const int n = lane & 15, g = lane >> 4;
    const int px0 = 16 * wid;
    const short* wA = (const short*)(ws + WOFF_OFF);

    f32x4 acc[4];
#pragma unroll
    for (int rf = 0; rf < 4; ++rf) acc[rf] = (f32x4){0.f,0.f,0.f,0.f};

    for (int c0 = 0; c0 < NC; c0 += 32) {
        __syncthreads();
        // stage 32 cins x 3 rows x 66 cols as bf16, 8-cin-packed b128 writes
        for (int e = tid; e < 3*66*4; e += 256) {
            int col = e % 66;
            int t2  = e / 66;
            int cg  = t2 & 3;
            int ky  = t2 >> 2;
            int y    = ho - 1 + ky;
            int gcol = wb + col - 1;
            float v[8];
            if ((unsigned)y < NH && (unsigned)gcol < NW) {
                const float* p = x + ((b*NC + c0 + 8*cg)*NH + y)*NW + gcol;
#pragma unroll
                for (int q = 0; q < 8; ++q) v[q] = p[q*NHW];
            } else {
#pragma unroll
                for (int q = 0; q < 8; ++q) v[q] = 0.f;
            }
            uint4 u = make_uint4(pack2(v[0],v[1]), pack2(v[2],v[3]),
                                 pack2(v[4],v[5]), pack2(v[6],v[7]));
            *(uint4*)&xs[ky][col][8*cg] = u;
        }
        __syncthreads();

#pragma unroll
        for (int k2 = 0; k2 < 9; ++k2) {
            const int ky = k2 / 3, kx = k2 % 3;
            short8 bf = *(const short8*)&xs[ky][px0 + n + kx][8*g];
#pragma unroll
            for (int rf = 0; rf < 4; ++rf) {
                short8 af = *(const short8*)&wA[((16*rf + n)*9 + k2)*128 + c0 + 8*g];
                acc[rf] = __builtin_amdgcn_mfma_f32_16x16x32_bf16(af, bf, acc[rf], 0,0,0);
            }
        }
    }

    // epilogue: route channels -> processed sy/sx/mask
    const int px = wb + px0 + n;
#pragma unroll
    for (int rf = 0; rf < 4; ++rf) {
#pragma unroll
        for (int r = 0; r < 4; ++r) {
            int cout = 16*rf + 4*g + r;
            if (cout >= 54) continue;
            float v = acc[rf][r] + b_off[cout];
            if (cout < 36) {
                int og = cout / 18, rem = cout - 18*og;
                int k2c = rem >> 1, d = cout & 1;
                float base = d ? (float)(px - 1 + (k2c % 3))
                              : (float)(ho - 1 + (k2c / 3));
                ws[(d ? SX_OFF : SY_OFF) + (((b*2+og)*9 + k2c)*NHW) + ho*NW + px] = v + base;
            } else {
                int cc = cout - 36;
                int og = cc / 9, k2c = cc - 9*og;
                ws[MK_OFF + (((b*2+og)*9 + k2c)*NHW) + ho*NW + px] = 1.f/(1.f+expf(-v));
            }
        }
    }
}

// ---------------------------------------------------------------------------
// deform: bilinear sample -> bf16 vals[64px][136cin] -> MFMA 128cout x 64px.
// Block = (b, ho, half-row). 256 threads = 4 waves.
//   sampling: px = tid&63 (coalesced gathers), grp = tid>>6 owns 32 cins.
//   MFMA: wave w owns all 128 couts x 16 px.
// ---------------------------------------------------------------------------
__global__ __launch_bounds__(256) void deform_kernel(
    const float* __restrict__ x, const float* __restrict__ ws,
    const float* __restrict__ bias, float* __restrict__ out)
{
    __shared__ short vals[64][136];   // 272B rows = 17*16B -> conflict-free b128
    int bid = blockIdx.x;
    bid = (bid & 7) * 128 + (bid >> 3);
    const int b   = bid >> 8;
    const int ho  = (bid >> 1) & 127;
    const int wb  = (bid & 1) * 64;
    const int tid = threadIdx.x;
    const int lane = tid & 63;
    const int wid = tid >> 6;
    const int n = lane & 15, g = lane >> 4;
    // sampling roles
    const int sp  = tid & 63;
    const int grp = tid >> 6;
    const int og  = grp >> 1;
    const int cb  = (grp & 1) * 32;
    const float* xb = x + (b*NC + og*64)*NHW;
    const short* wA = (const short*)(ws + WMAIN_OFF);

    f32x4 acc[8];
#pragma unroll
    for (int rf = 0; rf < 8; ++rf) acc[rf] = (f32x4){0.f,0.f,0.f,0.f};

    for (int k2 = 0; k2 < 9; ++k2) {
        // ---- prep (registers, recomputed per thread)
        const int sidx = (((b*2+og)*9 + k2)*NHW) + ho*NW + wb + sp;
        const float sy = ws[SY_OFF + sidx];
        const float sx = ws[SX_OFF + sidx];
        const float m  = ws[MK_OFF + sidx];
        const float y0f = floorf(sy), x0f = floorf(sx);
        const float ly = sy - y0f, lx = sx - x0f;
        const int y0 = (int)y0f, x0i = (int)x0f;
        const int y1 = y0 + 1, x1 = x0i + 1;
        const bool vy0 = (unsigned)y0 < NH, vy1 = (unsigned)y1 < NH;
        const bool vx0 = (unsigned)x0i < NW, vx1 = (unsigned)x1 < NW;
        const int cy0 = min(max(y0,0),NH-1), cy1 = min(max(y1,0),NH-1);
        const int cx0 = min(max(x0i,0),NW-1), cx1 = min(max(x1,0),NW-1);
        const int I0 = cy0*NW + cx0, I1 = cy0*NW + cx1;
        const int I2 = cy1*NW + cx0, I3 = cy1*NW + cx1;
        const float W0 = (vy0 && vx0) ? (1.f-ly)*(1.f-lx)*m : 0.f;
        const float W1 = (vy0 && vx1) ? (1.f-ly)*lx*m       : 0.f;
        const float W2 = (vy1 && vx0) ? ly*(1.f-lx)*m       : 0.f;
        const float W3 = (vy1 && vx1) ? ly*lx*m             : 0.f;

        __syncthreads();   // prev k2's MFMA reads done before overwrite
        // ---- sample 32 cins for this px, 8-cin-packed b128 writes
#pragma unroll
        for (int jj = 0; jj < 4; ++jj) {
            const int cc = cb + 8*jj;
            const float* p = xb + cc*NHW;
            float v[8];
#pragma unroll
            for (int q = 0; q < 8; ++q) {
                const float* pp = p + q*NHW;
                v[q] = W0*pp[I0] + W1*pp[I1] + W2*pp[I2] + W3*pp[I3];
            }
            uint4 u = make_uint4(pack2(v[0],v[1]), pack2(v[2],v[3]),
                                 pack2(v[4],v[5]), pack2(v[6],v[7]));
            *(uint4*)&vals[sp][og*64 + cc] = u;
        }
        __syncthreads();

        // ---- MFMA: acc[rf] over K=128 cins in 4 steps
#pragma unroll
        for (int ks = 0; ks < 4; ++ks) {
            short8 bf = *(const short8*)&vals[16*wid + n][32*ks + 8*g];
#pragma unroll
            for (int rf = 0; rf < 8; ++rf) {
                short8 af = *(const short8*)&wA[((16*rf + n)*9 + k2)*128 + 32*ks + 8*g];
                acc[rf] = __builtin_amdgcn_mfma_f32_16x16x32_bf16(af, bf, acc[rf], 0,0,0);
            }
        }
    }

    // ---- epilogue
    const int px = wb + 16*wid + n;
#pragma unroll
    for (int rf = 0; rf < 8; ++rf) {
#pragma unroll
        for (int r = 0; r < 4; ++r) {
            const int cout = 16*rf + 4*g + r;
            out[((b*NCOUT + cout)*NH + ho)*NW + px] = acc[rf][r] + bias[cout];
        }
    }
}

// ---------------------------------------------------------------------------
extern "C" void kernel_launch(void* const* d_in, const int* in_sizes, int n_in,
                              void* d_out, int out_size, void* d_ws, size_t ws_size,
                              hipStream_t stream)
{
    const float* x      = (const float*)d_in[0];
    const float* w_off  = (const float*)d_in[1];
    const float* b_off  = (const float*)d_in[2];
    const float* weight = (const float*)d_in[3];
    const float* bias   = (const float*)d_in[4];
    float* out = (float*)d_out;
    float* ws  = (float*)d_ws;

    hipLaunchKernelGGL(wtrans_kernel, dim3(864), dim3(256), 0, stream,
                       w_off, weight, ws);
    hipLaunchKernelGGL(offconv_kernel, dim3(NB*NH*2), dim3(256), 0, stream,
                       x, b_off, ws);
    hipLaunchKernelGGL(deform_kernel, dim3(NB*NH*2), dim3(256), 0, stream,
                       x, ws, bias, out);
}

// Round 3
// 299.508 us; speedup vs baseline: 2.7804x; 1.2243x over previous
//
#include <hip/hip_runtime.h>
#include <math.h>

#define NB 4
#define NC 128
#define NH 128
#define NW 128
#define NHW (NH*NW)
#define NCOUT 128

// ws float offsets
#define SY_OFF 0
#define SX_OFF 1179648
#define MK_OFF 2359296
#define WOFF_OFF 3538944    // bf16 wA_off: 64*1152 shorts (=36864 floats)
#define WMAIN_OFF 3575808   // bf16 swizzled main weights [k2][row][cin^] : 147456 shorts

typedef short short8 __attribute__((ext_vector_type(8)));
typedef float f32x4 __attribute__((ext_vector_type(4)));

__device__ inline short f2bf(float f) {
    unsigned u = __float_as_uint(f);
    u = (u + 0x7FFFu + ((u >> 16) & 1u)) >> 16;   // RNE
    return (short)u;
}
__device__ inline unsigned pack2(float lo, float hi) {
    return ((unsigned)(unsigned short)f2bf(lo)) |
           (((unsigned)(unsigned short)f2bf(hi)) << 16);
}

__device__ inline void gload_lds16(const void* g, void* l) {
    __builtin_amdgcn_global_load_lds(
        (const __attribute__((address_space(1))) unsigned int*)g,
        (__attribute__((address_space(3))) unsigned int*)l, 16, 0, 0);
}

// ---------------------------------------------------------------------------
// wtrans: offset-conv table [cout][k2][cin] (pad to 64 couts) +
//         main table PRE-SWIZZLED [k2][row][cin ^ ((row&7)*8)]
// ---------------------------------------------------------------------------
__global__ void wtrans_kernel(const float* __restrict__ w_off,
                              const float* __restrict__ weight,
                              float* __restrict__ ws)
{
    int i = blockIdx.x * 256 + threadIdx.x;
    if (i < 64*1152) {
        int cout = i / 1152, rem = i - cout*1152;
        int k2 = rem >> 7, cin = rem & 127;
        float v = (cout < 54) ? w_off[(cout*NC + cin)*9 + k2] : 0.f;
        ((short*)(ws + WOFF_OFF))[i] = f2bf(v);
    } else if (i < 64*1152 + 9*128*128) {
        int j = i - 64*1152;
        int k2 = j >> 14, rem = j & 16383;
        int row = rem >> 7, s = rem & 127;
        int cin = s ^ ((row & 7) * 8);          // inverse swizzle (involution)
        ((short*)(ws + WMAIN_OFF))[j] = f2bf(weight[(row*NC + cin)*9 + k2]);
    }
}

// ---------------------------------------------------------------------------
// offconv: 3x3 conv, 54 ch (pad 64) via MFMA. Block = (b, ho, half-row 64px).
// ---------------------------------------------------------------------------
__global__ __launch_bounds__(256) void offconv_kernel(
    const float* __restrict__ x, const float* __restrict__ b_off,
    float* __restrict__ ws)
{
    __shared__ short xs[3][66][40];
    int bid = blockIdx.x;
    bid = (bid & 7) * 128 + (bid >> 3);     // XCD swizzle (1024 = 8*128)
    const int b   = bid >> 8;
    const int ho  = (bid >> 1) & 127;
    const int wb  = (bid & 1) * 64;
    const int tid = threadIdx.x;
    const int lane = tid & 63;
    const int wid = tid >> 6;
    const int n = lane & 15, g = lane >> 4;
    const int px0 = 16 * wid;
    const short* wA = (const short*)(ws + WOFF_OFF);

    f32x4 acc[4];
#pragma unroll
    for (int rf = 0; rf < 4; ++rf) acc[rf] = (f32x4){0.f,0.f,0.f,0.f};

    for (int c0 = 0; c0 < NC; c0 += 32) {
        __syncthreads();
        for (int e = tid; e < 3*66*4; e += 256) {
            int col = e % 66;
            int t2  = e / 66;
            int cg  = t2 & 3;
            int ky  = t2 >> 2;
            int y    = ho - 1 + ky;
            int gcol = wb + col - 1;
            float v[8];
            if ((unsigned)y < NH && (unsigned)gcol < NW) {
                const float* p = x + ((b*NC + c0 + 8*cg)*NH + y)*NW + gcol;
#pragma unroll
                for (int q = 0; q < 8; ++q) v[q] = p[q*NHW];
            } else {
#pragma unroll
                for (int q = 0; q < 8; ++q) v[q] = 0.f;
            }
            uint4 u = make_uint4(pack2(v[0],v[1]), pack2(v[2],v[3]),
                                 pack2(v[4],v[5]), pack2(v[6],v[7]));
            *(uint4*)&xs[ky][col][8*cg] = u;
        }
        __syncthreads();

#pragma unroll
        for (int k2 = 0; k2 < 9; ++k2) {
            const int ky = k2 / 3, kx = k2 % 3;
            short8 bf = *(const short8*)&xs[ky][px0 + n + kx][8*g];
#pragma unroll
            for (int rf = 0; rf < 4; ++rf) {
                short8 af = *(const short8*)&wA[((16*rf + n)*9 + k2)*128 + c0 + 8*g];
                acc[rf] = __builtin_amdgcn_mfma_f32_16x16x32_bf16(af, bf, acc[rf], 0,0,0);
            }
        }
    }

    const int px = wb + px0 + n;
#pragma unroll
    for (int rf = 0; rf < 4; ++rf) {
#pragma unroll
        for (int r = 0; r < 4; ++r) {
            int cout = 16*rf + 4*g + r;
            if (cout >= 54) continue;
            float v = acc[rf][r] + b_off[cout];
            if (cout < 36) {
                int og = cout / 18, rem = cout - 18*og;
                int k2c = rem >> 1, d = cout & 1;
                float base = d ? (float)(px - 1 + (k2c % 3))
                              : (float)(ho - 1 + (k2c / 3));
                ws[(d ? SX_OFF : SY_OFF) + (((b*2+og)*9 + k2c)*NHW) + ho*NW + px] = v + base;
            } else {
                int cc = cout - 36;
                int og = cc / 9, k2c = cc - 9*og;
                ws[MK_OFF + (((b*2+og)*9 + k2c)*NHW) + ho*NW + px] = 1.f/(1.f+expf(-v));
            }
        }
    }
}

// ---------------------------------------------------------------------------
// deform: block = (b, ho): 128 px x 128 cout, 512 threads = 8 waves.
// Per k2: stage weight slab (32KB) via global_load_lds (async, overlaps
// sampling) -> sample 128px x 128cin into LDS -> MFMA from LDS only.
// Wave tile: 64 cout x 32 px.
// ---------------------------------------------------------------------------
__global__ __launch_bounds__(512, 4) void deform_kernel(
    const float* __restrict__ x, const float* __restrict__ ws,
    const float* __restrict__ bias, float* __restrict__ out)
{
    __shared__ short vals[128][136];    // 34816 B, 272B rows
    __shared__ short wslab[128*128];    // 32768 B, linear (source pre-swizzled)

    int bid = blockIdx.x;
    bid = (bid & 7) * 64 + (bid >> 3);      // XCD swizzle (512 = 8*64)
    const int b   = bid >> 7;
    const int ho  = bid & 127;
    const int tid = threadIdx.x;
    const int lane = tid & 63;
    const int wid = tid >> 6;               // 0..7
    const int n = lane & 15, g = lane >> 4;
    // MFMA roles: wave tile 64 cout x 32 px
    const int ch  = wid & 1;                // cout half
    const int pxq = wid >> 1;               // px quarter (32 px)
    // sampling roles
    const int sp  = tid & 127;              // pixel 0..127
    const int grp = tid >> 7;               // 0..3 -> 32-cin group
    const int og  = grp >> 1;
    const float* xb = x + (b*NC + grp*32)*NHW;
    const short* wswz = (const short*)(ws + WMAIN_OFF);

    f32x4 acc[4][2];
#pragma unroll
    for (int rf = 0; rf < 4; ++rf) {
        acc[rf][0] = (f32x4){0.f,0.f,0.f,0.f};
        acc[rf][1] = (f32x4){0.f,0.f,0.f,0.f};
    }

#pragma unroll 1
    for (int k2 = 0; k2 < 9; ++k2) {
        // ---- bilinear params (registers)
        const int sidx = (((b*2+og)*9 + k2)*NHW) + ho*NW + sp;
        const float sy = ws[SY_OFF + sidx];
        const float sx = ws[SX_OFF + sidx];
        const float m  = ws[MK_OFF + sidx];
        const float y0f = floorf(sy), x0f = floorf(sx);
        const float ly = sy - y0f, lx = sx - x0f;
        const int y0 = (int)y0f, x0i = (int)x0f;
        const int y1 = y0 + 1, x1 = x0i + 1;
        const bool vy0 = (unsigned)y0 < NH, vy1 = (unsigned)y1 < NH;
        const bool vx0 = (unsigned)x0i < NW, vx1 = (unsigned)x1 < NW;
        const int cy0 = min(max(y0,0),NH-1), cy1 = min(max(y1,0),NH-1);
        const int cx0 = min(max(x0i,0),NW-1), cx1 = min(max(x1,0),NW-1);
        const int I0 = cy0*NW + cx0, I1 = cy0*NW + cx1;
        const int I2 = cy1*NW + cx0, I3 = cy1*NW + cx1;
        const float W0 = (vy0 && vx0) ? (1.f-ly)*(1.f-lx)*m : 0.f;
        const float W1 = (vy0 && vx1) ? (1.f-ly)*lx*m       : 0.f;
        const float W2 = (vy1 && vx0) ? ly*(1.f-lx)*m       : 0.f;
        const float W3 = (vy1 && vx1) ? ly*lx*m             : 0.f;

        __syncthreads();   // prev MFMA done reading vals + wslab

        // ---- async weight stage: 32KB slab for this k2 (overlaps sampling)
        {
            const short* wk = wswz + (k2 << 14);
#pragma unroll
            for (int j = 0; j < 4; ++j)
                gload_lds16(wk + (j*512 + tid)*8, &wslab[(j*512 + tid)*8]);
        }

        // ---- sample 32 cins for px sp, 8-cin-packed b128 writes
#pragma unroll
        for (int jj = 0; jj < 4; ++jj) {
            const float* p = xb + 8*jj*NHW;
            float v[8];
#pragma unroll
            for (int q = 0; q < 8; ++q) {
                const float* pp = p + q*NHW;
                v[q] = W0*pp[I0] + W1*pp[I1] + W2*pp[I2] + W3*pp[I3];
            }
            uint4 u = make_uint4(pack2(v[0],v[1]), pack2(v[2],v[3]),
                                 pack2(v[4],v[5]), pack2(v[6],v[7]));
            *(uint4*)&vals[sp][grp*32 + 8*jj] = u;
        }
        __syncthreads();   // vals written; vmcnt drained -> wslab ready

        // ---- MFMA from LDS only
#pragma unroll
        for (int ks = 0; ks < 4; ++ks) {
            short8 bf0 = *(const short8*)&vals[pxq*32      + n][ks*32 + 8*g];
            short8 bf1 = *(const short8*)&vals[pxq*32 + 16 + n][ks*32 + 8*g];
#pragma unroll
            for (int rf = 0; rf < 4; ++rf) {
                const int row = ch*64 + rf*16 + n;
                short8 af = *(const short8*)&wslab[row*128 + ((ks*32 + g*8) ^ ((n&7)*8))];
                acc[rf][0] = __builtin_amdgcn_mfma_f32_16x16x32_bf16(af, bf0, acc[rf][0], 0,0,0);
                acc[rf][1] = __builtin_amdgcn_mfma_f32_16x16x32_bf16(af, bf1, acc[rf][1], 0,0,0);
            }
        }
    }

    // ---- epilogue
#pragma unroll
    for (int rf = 0; rf < 4; ++rf) {
#pragma unroll
        for (int pxb = 0; pxb < 2; ++pxb) {
            const int px = pxq*32 + pxb*16 + n;
#pragma unroll
            for (int r = 0; r < 4; ++r) {
                const int cout = ch*64 + rf*16 + 4*g + r;
                out[((b*NCOUT + cout)*NH + ho)*NW + px] = acc[rf][pxb][r] + bias[cout];
            }
        }
    }
}

// ---------------------------------------------------------------------------
extern "C" void kernel_launch(void* const* d_in, const int* in_sizes, int n_in,
                              void* d_out, int out_size, void* d_ws, size_t ws_size,
                              hipStream_t stream)
{
    const float* x      = (const float*)d_in[0];
    const float* w_off  = (const float*)d_in[1];
    const float* b_off  = (const float*)d_in[2];
    const float* weight = (const float*)d_in[3];
    const float* bias   = (const float*)d_in[4];
    float* out = (float*)d_out;
    float* ws  = (float*)d_ws;

    hipLaunchKernelGGL(wtrans_kernel, dim3(864), dim3(256), 0, stream,
                       w_off, weight, ws);
    hipLaunchKernelGGL(offconv_kernel, dim3(NB*NH*2), dim3(256), 0, stream,
                       x, b_off, ws);
    hipLaunchKernelGGL(deform_kernel, dim3(NB*NH), dim3(512), 0, stream,
                       x, ws, bias, out);
}

// Round 4
// 274.200 us; speedup vs baseline: 3.0370x; 1.0923x over previous
//
#include <hip/hip_runtime.h>
#include <math.h>

#define NB 4
#define NC 128
#define NH 128
#define NW 128
#define NHW (NH*NW)
#define NCOUT 128

// ws float offsets
#define SY_OFF 0
#define SX_OFF 1179648
#define MK_OFF 2359296
#define WOFF_OFF 3538944    // bf16 wA_off: 64*1152 shorts
#define WMAIN_OFF 3575808   // bf16 main weights, 36 slabs of [128cout][32cin] shorts

typedef short short8 __attribute__((ext_vector_type(8)));
typedef float f32x4 __attribute__((ext_vector_type(4)));

__device__ inline short f2bf(float f) {
    unsigned u = __float_as_uint(f);
    u = (u + 0x7FFFu + ((u >> 16) & 1u)) >> 16;   // RNE
    return (short)u;
}
__device__ inline unsigned pack2(float lo, float hi) {
    return ((unsigned)(unsigned short)f2bf(lo)) |
           (((unsigned)(unsigned short)f2bf(hi)) << 16);
}
__device__ inline void gload_lds16(const void* g, void* l) {
    __builtin_amdgcn_global_load_lds(
        (const __attribute__((address_space(1))) unsigned int*)g,
        (__attribute__((address_space(3))) unsigned int*)l, 16, 0, 0);
}

// ---------------------------------------------------------------------------
// wtrans: offset-conv table [cout][k2][cin] (pad 64) +
//         main table as 36 slabs: [(chunk*9+k2)][cout][cin-in-chunk(32)]
// ---------------------------------------------------------------------------
__global__ void wtrans_kernel(const float* __restrict__ w_off,
                              const float* __restrict__ weight,
                              float* __restrict__ ws)
{
    int i = blockIdx.x * 256 + threadIdx.x;
    if (i < 64*1152) {
        int cout = i / 1152, rem = i - cout*1152;
        int k2 = rem >> 7, cin = rem & 127;
        float v = (cout < 54) ? w_off[(cout*NC + cin)*9 + k2] : 0.f;
        ((short*)(ws + WOFF_OFF))[i] = f2bf(v);
    } else if (i < 64*1152 + 36*4096) {
        int j = i - 64*1152;
        int s = j >> 12, rem = j & 4095;
        int cout = rem >> 5, c = rem & 31;
        int chunk = s / 9, k2 = s - 9*chunk;
        ((short*)(ws + WMAIN_OFF))[j] =
            f2bf(weight[(cout*NC + chunk*32 + c)*9 + k2]);
    }
}

// ---------------------------------------------------------------------------
// offconv: 3x3 conv, 54 ch (pad 64) via MFMA. Block = (b, ho, half-row 64px).
// ---------------------------------------------------------------------------
__global__ __launch_bounds__(256) void offconv_kernel(
    const float* __restrict__ x, const float* __restrict__ b_off,
    float* __restrict__ ws)
{
    __shared__ short xs[3][66][40];
    int bid = blockIdx.x;
    bid = (bid & 7) * 128 + (bid >> 3);     // XCD swizzle (1024 = 8*128)
    const int b   = bid >> 8;
    const int ho  = (bid >> 1) & 127;
    const int wb  = (bid & 1) * 64;
    const int tid = threadIdx.x;
    const int lane = tid & 63;
    const int wid = tid >> 6;
    const int n = lane & 15, g = lane >> 4;
    const int px0 = 16 * wid;
    const short* wA = (const short*)(ws + WOFF_OFF);

    f32x4 acc[4];
#pragma unroll
    for (int rf = 0; rf < 4; ++rf) acc[rf] = (f32x4){0.f,0.f,0.f,0.f};

    for (int c0 = 0; c0 < NC; c0 += 32) {
        __syncthreads();
        for (int e = tid; e < 3*66*4; e += 256) {
            int col = e % 66;
            int t2  = e / 66;
            int cg  = t2 & 3;
            int ky  = t2 >> 2;
            int y    = ho - 1 + ky;
            int gcol = wb + col - 1;
            float v[8];
            if ((unsigned)y < NH && (unsigned)gcol < NW) {
                const float* p = x + ((b*NC + c0 + 8*cg)*NH + y)*NW + gcol;
#pragma unroll
                for (int q = 0; q < 8; ++q) v[q] = p[q*NHW];
            } else {
#pragma unroll
                for (int q = 0; q < 8; ++q) v[q] = 0.f;
            }
            uint4 u = make_uint4(pack2(v[0],v[1]), pack2(v[2],v[3]),
                                 pack2(v[4],v[5]), pack2(v[6],v[7]));
            *(uint4*)&xs[ky][col][8*cg] = u;
        }
        __syncthreads();

#pragma unroll
        for (int k2 = 0; k2 < 9; ++k2) {
            const int ky = k2 / 3, kx = k2 % 3;
            short8 bf = *(const short8*)&xs[ky][px0 + n + kx][8*g];
#pragma unroll
            for (int rf = 0; rf < 4; ++rf) {
                short8 af = *(const short8*)&wA[((16*rf + n)*9 + k2)*128 + c0 + 8*g];
                acc[rf] = __builtin_amdgcn_mfma_f32_16x16x32_bf16(af, bf, acc[rf], 0,0,0);
            }
        }
    }

    const int px = wb + px0 + n;
#pragma unroll
    for (int rf = 0; rf < 4; ++rf) {
#pragma unroll
        for (int r = 0; r < 4; ++r) {
            int cout = 16*rf + 4*g + r;
            if (cout >= 54) continue;
            float v = acc[rf][r] + b_off[cout];
            if (cout < 36) {
                int og = cout / 18, rem = cout - 18*og;
                int k2c = rem >> 1, d = cout & 1;
                float base = d ? (float)(px - 1 + (k2c % 3))
                              : (float)(ho - 1 + (k2c / 3));
                ws[(d ? SX_OFF : SY_OFF) + (((b*2+og)*9 + k2c)*NHW) + ho*NW + px] = v + base;
            } else {
                int cc = cout - 36;
                int og = cc / 9, k2c = cc - 9*og;
                ws[MK_OFF + (((b*2+og)*9 + k2c)*NHW) + ho*NW + px] = 1.f/(1.f+expf(-v));
            }
        }
    }
}

// ---------------------------------------------------------------------------
// deform: block = (b, ho): 128 px x 128 cout, 512 threads = 8 waves.
// cin-chunk OUTER (32 cins, L2-resident), k2 inner. 36 slab-iterations.
// Bilinear params precomputed per og-half into LDS. Weight slabs (8KB)
// double-buffered via global_load_lds, prefetched 1 iter ahead. vals dbuf.
// Wave tile: 64 cout x 32 px, K=32 per iter.
// ---------------------------------------------------------------------------
__global__ __launch_bounds__(512, 4) void deform_kernel(
    const float* __restrict__ x, const float* __restrict__ ws,
    const float* __restrict__ bias, float* __restrict__ out)
{
    __shared__ int4   pI[9][128];        // 18432 B (byte offsets, clipped)
    __shared__ float4 pW[9][128];        // 18432 B (validity*mask folded)
    __shared__ short  vals[2][128][40];  // 20480 B, 80B rows (16B-aligned, bank-even)
    __shared__ short  wslab[2][4096];    // 16384 B, [cout][32cin]

    int bid = blockIdx.x;
    bid = (bid & 7) * 64 + (bid >> 3);      // XCD swizzle (512 = 8*64)
    const int b   = bid >> 7;
    const int ho  = bid & 127;
    const int tid = threadIdx.x;
    const int lane = tid & 63;
    const int wid = tid >> 6;               // 0..7
    const int n = lane & 15, g = lane >> 4;
    const int ch  = wid & 1;                // cout half (MFMA role)
    const int pxq = wid >> 1;               // px quarter (MFMA role)
    const int sp  = tid & 127;              // pixel (sampling role)
    const int sub = tid >> 7;               // 8-cin subgroup (sampling role)
    const short* wmn = (const short*)(ws + WMAIN_OFF);
    const char*  xB  = (const char*)(x + (long)b*NC*NHW);

    f32x4 acc[4][2];
#pragma unroll
    for (int rf = 0; rf < 4; ++rf) {
        acc[rf][0] = (f32x4){0.f,0.f,0.f,0.f};
        acc[rf][1] = (f32x4){0.f,0.f,0.f,0.f};
    }

    auto SAMPLE = [&](int it, int buf) {
        const int chunk = it / 9;
        const int k2 = it - 9*chunk;
        const int4  I  = pI[k2][sp];
        const float4 Wv = pW[k2][sp];
        const char* xc = xB + (long)(chunk*32 + sub*8) * (NHW*4);
        float c0[8], c1[8], c2[8], c3[8];
#pragma unroll
        for (int q = 0; q < 8; ++q) {
            const char* p = xc + q*(NHW*4);
            c0[q] = *(const float*)(p + I.x);
            c1[q] = *(const float*)(p + I.y);
            c2[q] = *(const float*)(p + I.z);
            c3[q] = *(const float*)(p + I.w);
        }
        uint4 u;
        unsigned* up = (unsigned*)&u;
#pragma unroll
        for (int q = 0; q < 4; ++q) {
            float va = Wv.x*c0[2*q]   + Wv.y*c1[2*q]   + Wv.z*c2[2*q]   + Wv.w*c3[2*q];
            float vb = Wv.x*c0[2*q+1] + Wv.y*c1[2*q+1] + Wv.z*c2[2*q+1] + Wv.w*c3[2*q+1];
            up[q] = pack2(va, vb);
        }
        *(uint4*)&vals[buf][sp][sub*8] = u;
    };

    // prologue: DMA slab 0
    gload_lds16(wmn + tid*8, &wslab[0][tid*8]);

#pragma unroll 1
    for (int og = 0; og < 2; ++og) {
        if (og) __syncthreads();            // prior half fully done
        // ---- build bilinear params for this og
        for (int e = tid; e < 1152; e += 512) {
            const int k2 = e >> 7, px = e & 127;
            const int sidx = (((b*2+og)*9 + k2)*NHW) + ho*NW + px;
            const float sy = ws[SY_OFF + sidx];
            const float sx = ws[SX_OFF + sidx];
            const float m  = ws[MK_OFF + sidx];
            const float y0f = floorf(sy), x0f = floorf(sx);
            const float ly = sy - y0f, lx = sx - x0f;
            const int y0 = (int)y0f, x0i = (int)x0f;
            const int y1 = y0 + 1, x1 = x0i + 1;
            const bool vy0 = (unsigned)y0 < NH, vy1 = (unsigned)y1 < NH;
            const bool vx0 = (unsigned)x0i < NW, vx1 = (unsigned)x1 < NW;
            const int cy0 = min(max(y0,0),NH-1), cy1 = min(max(y1,0),NH-1);
            const int cx0 = min(max(x0i,0),NW-1), cx1 = min(max(x1,0),NW-1);
            pI[k2][px] = make_int4((cy0*NW + cx0)*4, (cy0*NW + cx1)*4,
                                   (cy1*NW + cx0)*4, (cy1*NW + cx1)*4);
            pW[k2][px] = make_float4(
                (vy0 && vx0) ? (1.f-ly)*(1.f-lx)*m : 0.f,
                (vy0 && vx1) ? (1.f-ly)*lx*m       : 0.f,
                (vy1 && vx0) ? ly*(1.f-lx)*m       : 0.f,
                (vy1 && vx1) ? ly*lx*m             : 0.f);
        }
        __syncthreads();

        const int it0 = og*18;
        SAMPLE(it0, 0);                     // it0 is even -> buf 0
        __syncthreads();

#pragma unroll 1
        for (int it = it0; it < it0 + 18; ++it) {
            const int cur = it & 1, nxt = cur ^ 1;
            if (it < it0 + 17) {
                gload_lds16(wmn + (it+1)*4096 + tid*8, &wslab[nxt][tid*8]);
                SAMPLE(it+1, nxt);
            } else if (og == 0) {
                gload_lds16(wmn + 18*4096 + tid*8, &wslab[nxt][tid*8]);
            }
            // ---- MFMA from LDS only (K=32)
            {
                short8 bf0 = *(const short8*)&vals[cur][pxq*32 + n][8*g];
                short8 bf1 = *(const short8*)&vals[cur][pxq*32 + 16 + n][8*g];
#pragma unroll
                for (int rf = 0; rf < 4; ++rf) {
                    short8 af = *(const short8*)&wslab[cur][(ch*64 + rf*16 + n)*32 + 8*g];
                    acc[rf][0] = __builtin_amdgcn_mfma_f32_16x16x32_bf16(af, bf0, acc[rf][0], 0,0,0);
                    acc[rf][1] = __builtin_amdgcn_mfma_f32_16x16x32_bf16(af, bf1, acc[rf][1], 0,0,0);
                }
            }
            __syncthreads();
        }
    }

    // ---- epilogue
#pragma unroll
    for (int rf = 0; rf < 4; ++rf) {
#pragma unroll
        for (int pxb = 0; pxb < 2; ++pxb) {
            const int px = pxq*32 + pxb*16 + n;
#pragma unroll
            for (int r = 0; r < 4; ++r) {
                const int cout = ch*64 + rf*16 + 4*g + r;
                out[((b*NCOUT + cout)*NH + ho)*NW + px] = acc[rf][pxb][r] + bias[cout];
            }
        }
    }
}

// ---------------------------------------------------------------------------
extern "C" void kernel_launch(void* const* d_in, const int* in_sizes, int n_in,
                              void* d_out, int out_size, void* d_ws, size_t ws_size,
                              hipStream_t stream)
{
    const float* x      = (const float*)d_in[0];
    const float* w_off  = (const float*)d_in[1];
    const float* b_off  = (const float*)d_in[2];
    const float* weight = (const float*)d_in[3];
    const float* bias   = (const float*)d_in[4];
    float* out = (float*)d_out;
    float* ws  = (float*)d_ws;

    hipLaunchKernelGGL(wtrans_kernel, dim3(864), dim3(256), 0, stream,
                       w_off, weight, ws);
    hipLaunchKernelGGL(offconv_kernel, dim3(NB*NH*2), dim3(256), 0, stream,
                       x, b_off, ws);
    hipLaunchKernelGGL(deform_kernel, dim3(NB*NH), dim3(512), 0, stream,
                       x, ws, bias, out);
}